// Round 4
// baseline (165.036 us; speedup 1.0000x reference)
//
#include <hip/hip_runtime.h>
#include <stdint.h>

#define SC_LOG2E 0.18033688011112042f  // (1/8) * log2(e)

typedef __attribute__((ext_vector_type(8))) short short8;
typedef __attribute__((ext_vector_type(4))) float f32x4;

__device__ __forceinline__ unsigned short f2bf(float f) {
  unsigned int u = __float_as_uint(f);
  u += 0x7fffu + ((u >> 16) & 1u);
  return (unsigned short)(u >> 16);
}

__device__ __forceinline__ void gload_lds16(const void* g, void* l) {
  __builtin_amdgcn_global_load_lds((const __attribute__((address_space(1))) void*)g,
                                   (__attribute__((address_space(3))) void*)l,
                                   16, 0, 0);
}

__device__ __forceinline__ f32x4 mfma16(short8 a, short8 b, f32x4 c) {
  return __builtin_amdgcn_mfma_f32_16x16x32_bf16(a, b, c, 0, 0, 0);
}

// ---------------- prep kernels ----------------

// fused: cast x -> bf16 AND per-16-row block sums -> bf16 (x read once)
__global__ __launch_bounds__(256) void prep_x_k(const float* __restrict__ x,
                                                unsigned short* __restrict__ xb,
                                                unsigned short* __restrict__ gb) {
  int gr = blockIdx.x;   // 0..511 = b*256 + g
  int c4 = threadIdx.x;  // col group of 4
  const float4* p = (const float4*)(x + (size_t)gr * 16384) + c4;
  float4 s = {0.f, 0.f, 0.f, 0.f};
#pragma unroll
  for (int t = 0; t < 16; ++t) {
    float4 v = p[(size_t)t * 256];
    ushort4 o;
    o.x = f2bf(v.x); o.y = f2bf(v.y); o.z = f2bf(v.z); o.w = f2bf(v.w);
    ((ushort4*)xb)[(size_t)(gr * 16 + t) * 256 + c4] = o;
    s.x += v.x; s.y += v.y; s.z += v.z; s.w += v.w;
  }
  ushort4 og;
  og.x = f2bf(s.x); og.y = f2bf(s.y); og.z = f2bf(s.z); og.w = f2bf(s.w);
  ((ushort4*)gb)[(size_t)gr * 256 + c4] = og;
}

// transpose 4x [1024][1024] f32 weights -> bf16 [N][K]; Wq pre-scaled by SC_LOG2E
__global__ __launch_bounds__(256) void transpose_w4_k(
    const float* __restrict__ wq, const float* __restrict__ wk,
    const float* __restrict__ wv, const float* __restrict__ wo,
    unsigned short* __restrict__ wqkv_t, unsigned short* __restrict__ wo_t) {
  __shared__ float tile[64 * 65];
  int z = blockIdx.z;
  const float* src = (z == 0) ? wq : (z == 1) ? wk : (z == 2) ? wv : wo;
  unsigned short* dst = (z == 3) ? wo_t : (wqkv_t + (size_t)z * 1048576);
  float scale = (z == 0) ? SC_LOG2E : 1.0f;
  int tc = blockIdx.x * 64, tr = blockIdx.y * 64;
  int cx = threadIdx.x & 63, ry = threadIdx.x >> 6;
#pragma unroll
  for (int i = 0; i < 16; ++i) {
    int r = ry + i * 4;
    tile[r * 65 + cx] = src[(size_t)(tr + r) * 1024 + tc + cx];
  }
  __syncthreads();
#pragma unroll
  for (int i = 0; i < 16; ++i) {
    int r = ry + i * 4;
    dst[(size_t)(tc + r) * 1024 + tr + cx] = f2bf(tile[cx * 65 + r] * scale);
  }
}

// generic bf16 transpose: dst[c][r] = src[r][c], 64x64 tiles, z-batched
__global__ __launch_bounds__(256) void transpose_bf16_k(
    const unsigned short* __restrict__ src, int sstride, size_t szstride,
    unsigned short* __restrict__ dst, int dstride, size_t dzstride) {
  __shared__ unsigned short tile[64 * 65];
  src += blockIdx.z * szstride;
  dst += blockIdx.z * dzstride;
  int tc = blockIdx.x * 64, tr = blockIdx.y * 64;
  int cx = threadIdx.x & 63, ry = threadIdx.x >> 6;
#pragma unroll
  for (int i = 0; i < 16; ++i) {
    int r = ry + i * 4;
    tile[r * 65 + cx] = src[(size_t)(tr + r) * sstride + tc + cx];
  }
  __syncthreads();
#pragma unroll
  for (int i = 0; i < 16; ++i) {
    int r = ry + i * 4;
    dst[(size_t)(tc + r) * dstride + tr + cx] = tile[cx * 65 + r];
  }
}

// ------- 256x256 2-phase GEMM (T1+T2+T3+T4+T5): C[M][N]=A[M][K]*Bt[N][K]^T -------
// 512 threads = 8 waves (2M x 4N); BK=64; 128KB LDS double-buffer; counted vmcnt.
// Phase A: read A(mi0-3)+B(all 4 ni, both kk; B kept live in regs), stage A2(t+1),
//          vmcnt(8), bar, 32 MFMA (mi0-3 x ni0-3), bar.
// Phase B: read A(mi4-7), stage A1/B1/B2(t+2), vmcnt(8), bar, 32 MFMA, bar.
// Regions: A1 = A rows {0-63,128-191} (read phA), A2 = {64-127,192-255} (phB),
// B1/B2 = row 32-groups even/odd (both read phA). Each region is staged in the
// phase AFTER its last read of the aliasing buffer -> no read/overwrite race.
__global__ __launch_bounds__(512, 2) void gemm256_k(
    const unsigned short* __restrict__ A, const unsigned short* __restrict__ Bt,
    unsigned short* __restrict__ C, int M, int N, int K, int nbn) {
  __shared__ unsigned short lds[2][2][16384];  // [buf][A/B][256*64]
  int nwg = gridDim.x, cpx = nwg >> 3;
  int bid = blockIdx.x;
  bid = (bid & 7) * cpx + (bid >> 3);  // XCD swizzle (grid % 8 == 0)
  int bm = bid / nbn, bn = bid % nbn;
  int lane = threadIdx.x & 63, w = threadIdx.x >> 6;
  int wm = w >> 2, wn = w & 3;
  int l15 = lane & 15, lg = lane >> 4;
  int lrow = lane >> 3;
  int lcol = ((lane & 7) ^ lrow) * 8;  // pre-swizzled source col granule
  const int KT = K >> 6;

  const unsigned short* Ab = A + ((size_t)bm * 256 + lrow) * K + lcol;
  const unsigned short* Bb = Bt + ((size_t)bn * 256 + lrow) * K + lcol;

  // precomputed per-lane swizzled LDS read offsets (bytes within A/B half)
  int x0 = 2 * ((lg * 8) ^ ((l15 & 7) * 8));          // kk=0
  int x1 = 2 * ((32 | (lg * 8)) ^ ((l15 & 7) * 8));   // kk=1
  int aoff0 = (wm * 128 + l15) * 128 + x0;
  int aoff1 = (wm * 128 + l15) * 128 + x1;
  int boff0 = (wn * 64 + l15) * 128 + x0;
  int boff1 = (wn * 64 + l15) * 128 + x1;

  f32x4 zero4 = {0.f, 0.f, 0.f, 0.f};
  f32x4 acc[8][4];
#pragma unroll
  for (int i = 0; i < 8; ++i)
#pragma unroll
    for (int j = 0; j < 4; ++j) acc[i][j] = zero4;

  // stage one 16KB region (2 x gload_lds per thread) of K-tile t
  auto stage = [&](int kind, int t) {  // 0=A1 1=A2 2=B1 3=B2
    if (t >= KT) return;
    const unsigned short* src = (kind < 2) ? Ab : Bb;
#pragma unroll
    for (int i = 0; i < 2; ++i) {
      int q = i * 64 + w * 8;
      int r0;
      if (kind == 0)      r0 = (q & 63) + ((q >> 6) << 7);
      else if (kind == 1) r0 = (q & 63) + ((q >> 6) << 7) + 64;
      else if (kind == 2) r0 = (q & 31) + ((q >> 5) << 6);
      else                r0 = (q & 31) + ((q >> 5) << 6) + 32;
      gload_lds16(src + (size_t)r0 * K + t * 64,
                  &lds[t & 1][kind < 2 ? 0 : 1][r0 * 64]);
    }
  };

  // prologue: tile0 all 4 regions + tile1 {A1,B1,B2}; vmcnt(6) -> tile0 landed
  stage(0, 0); stage(2, 0); stage(3, 0); stage(1, 0);
  stage(0, 1); stage(2, 1); stage(3, 1);
  asm volatile("s_waitcnt vmcnt(6)" ::: "memory");
  __builtin_amdgcn_s_barrier();

  for (int t = 0; t < KT; ++t) {
    const char* bufA = (const char*)&lds[t & 1][0][0];
    const char* bufB = (const char*)&lds[t & 1][1][0];
    short8 aF[4][2], bF[4][2];
    // ================= phase A =================
#pragma unroll
    for (int mi = 0; mi < 4; ++mi) {
      aF[mi][0] = *(const short8*)(bufA + aoff0 + mi * 2048);
      aF[mi][1] = *(const short8*)(bufA + aoff1 + mi * 2048);
    }
#pragma unroll
    for (int ni = 0; ni < 4; ++ni) {
      bF[ni][0] = *(const short8*)(bufB + boff0 + ni * 2048);
      bF[ni][1] = *(const short8*)(bufB + boff1 + ni * 2048);
    }
    stage(1, t + 1);  // A2(t+1)
    if (t < KT - 2)
      asm volatile("s_waitcnt vmcnt(8)" ::: "memory");
    else
      asm volatile("s_waitcnt vmcnt(0)" ::: "memory");
    __builtin_amdgcn_s_barrier();
    __builtin_amdgcn_s_setprio(1);
#pragma unroll
    for (int kk = 0; kk < 2; ++kk)
#pragma unroll
      for (int mi = 0; mi < 4; ++mi)
#pragma unroll
        for (int ni = 0; ni < 4; ++ni)
          acc[mi][ni] = mfma16(aF[mi][kk], bF[ni][kk], acc[mi][ni]);
    __builtin_amdgcn_s_setprio(0);
    __builtin_amdgcn_s_barrier();
    // ================= phase B =================
#pragma unroll
    for (int mi = 0; mi < 4; ++mi) {
      aF[mi][0] = *(const short8*)(bufA + aoff0 + (mi + 4) * 2048);
      aF[mi][1] = *(const short8*)(bufA + aoff1 + (mi + 4) * 2048);
    }
    stage(0, t + 2); stage(2, t + 2); stage(3, t + 2);
    if (t < KT - 2)
      asm volatile("s_waitcnt vmcnt(8)" ::: "memory");
    else
      asm volatile("s_waitcnt vmcnt(0)" ::: "memory");
    __builtin_amdgcn_s_barrier();
    __builtin_amdgcn_s_setprio(1);
#pragma unroll
    for (int kk = 0; kk < 2; ++kk)
#pragma unroll
      for (int mi = 0; mi < 4; ++mi)
#pragma unroll
        for (int ni = 0; ni < 4; ++ni)
          acc[mi + 4][ni] = mfma16(aF[mi][kk], bF[ni][kk], acc[mi + 4][ni]);
    __builtin_amdgcn_s_setprio(0);
    __builtin_amdgcn_s_barrier();
  }

#pragma unroll
  for (int mi = 0; mi < 8; ++mi) {
    size_t row = (size_t)bm * 256 + wm * 128 + mi * 16 + lg * 4;
#pragma unroll
    for (int ni = 0; ni < 4; ++ni) {
      size_t col = (size_t)bn * 256 + wn * 64 + ni * 16 + l15;
#pragma unroll
      for (int r = 0; r < 4; ++r)
        C[(row + r) * N + col] = f2bf(acc[mi][ni][r]);
    }
  }
}

// ---------------- GEMM m97 structure (f32 out, used for output projection) -------
template <bool F32OUT>
__global__ __launch_bounds__(256) void gemm_bt_k(
    const unsigned short* __restrict__ A, const unsigned short* __restrict__ Bt,
    void* __restrict__ Cv, int M, int N, int K, int nbn) {
  __shared__ unsigned short Alds[128 * 64];
  __shared__ unsigned short Blds[128 * 64];
  int bid = blockIdx.x;
  int bm = bid / nbn, bn = bid % nbn;
  int lane = threadIdx.x & 63, wid = threadIdx.x >> 6;
  int wr = wid >> 1, wc = wid & 1;
  int l15 = lane & 15, lg = lane >> 4;

  f32x4 zero4 = {0.f, 0.f, 0.f, 0.f};
  f32x4 acc[4][4];
#pragma unroll
  for (int i = 0; i < 4; ++i)
#pragma unroll
    for (int j = 0; j < 4; ++j) acc[i][j] = zero4;

  int srow[4], scol[4];
#pragma unroll
  for (int i = 0; i < 4; ++i) {
    int seg = wid * 4 + i;
    int r = seg * 8 + (lane >> 3);
    srow[i] = r;
    scol[i] = ((lane & 7) ^ (r & 7)) * 8;
  }
  size_t arow0 = (size_t)bm * 128, brow0 = (size_t)bn * 128;

  int ksteps = K >> 6;
  for (int ks = 0; ks < ksteps; ++ks) {
    int k0 = ks << 6;
#pragma unroll
    for (int i = 0; i < 4; ++i) {
      gload_lds16(A + (arow0 + srow[i]) * K + k0 + scol[i],
                  (char*)Alds + (wid * 4 + i) * 1024);
      gload_lds16(Bt + (brow0 + srow[i]) * K + k0 + scol[i],
                  (char*)Blds + (wid * 4 + i) * 1024);
    }
    __syncthreads();
#pragma unroll
    for (int kk = 0; kk < 2; ++kk) {
      short8 af[4], bfr[4];
#pragma unroll
      for (int mi = 0; mi < 4; ++mi) {
        int r = wr * 64 + mi * 16 + l15;
        af[mi] = *(const short8*)((const char*)Alds + r * 128 +
                                  ((kk * 64 + lg * 16) ^ ((r & 7) << 4)));
      }
#pragma unroll
      for (int ni = 0; ni < 4; ++ni) {
        int r = wc * 64 + ni * 16 + l15;
        bfr[ni] = *(const short8*)((const char*)Blds + r * 128 +
                                   ((kk * 64 + lg * 16) ^ ((r & 7) << 4)));
      }
#pragma unroll
      for (int mi = 0; mi < 4; ++mi)
#pragma unroll
        for (int ni = 0; ni < 4; ++ni)
          acc[mi][ni] = mfma16(af[mi], bfr[ni], acc[mi][ni]);
    }
    __syncthreads();
  }
  int rq = lg << 2;
#pragma unroll
  for (int mi = 0; mi < 4; ++mi) {
    size_t row = arow0 + wr * 64 + mi * 16 + rq;
#pragma unroll
    for (int ni = 0; ni < 4; ++ni) {
      size_t col = brow0 + wc * 64 + ni * 16 + l15;
#pragma unroll
      for (int r = 0; r < 4; ++r) {
        if (F32OUT)
          ((float*)Cv)[(row + r) * N + col] = acc[mi][ni][r];
        else
          ((unsigned short*)Cv)[(row + r) * N + col] = f2bf(acc[mi][ni][r]);
      }
    }
  }
}

// ---------------- fused local+global flash attention (m=0 softmax) ----------------
// grid = B*H*nb (n fastest); block = 256 (4 waves x 32 q-rows)
// qkv: [8704][3072] = rows 0..8191 token q|k|v, rows 8192..8703 side g-rows
__global__ __launch_bounds__(256) void attn_k(
    const unsigned short* __restrict__ qkv,
    const unsigned short* __restrict__ v_t,       // [B][1024][L]
    const unsigned short* __restrict__ side_v_t,  // [B][1024][G]
    unsigned short* __restrict__ y) {             // [B*L][1024]
  const int L = 4096, G = 256;
  __shared__ unsigned short K0[4096], V0[4096];  // [key][d] / [d][key], swizzled
  __shared__ unsigned short K1[4096], V1[4096];
  __shared__ unsigned short Pl[4][2048];         // per-wave P [32 q][64 k]

  int bid = blockIdx.x;
  int n = bid & 31, h = (bid >> 5) & 15, b = bid >> 9;
  int lane = threadIdx.x & 63, wid = threadIdx.x >> 6;
  int l15 = lane & 15, lg = lane >> 4, rq = lg << 2;

  short8 qf[2][2];
  {
    size_t rowb = (size_t)b * L + n * 128 + wid * 32;
#pragma unroll
    for (int qt = 0; qt < 2; ++qt)
#pragma unroll
      for (int kk = 0; kk < 2; ++kk)
        qf[qt][kk] = *(const short8*)(qkv + (rowb + qt * 16 + l15) * 3072 +
                                      h * 64 + kk * 32 + lg * 8);
  }

  f32x4 zero4 = {0.f, 0.f, 0.f, 0.f};
  f32x4 accO[2][4], accSum[2];
#pragma unroll
  for (int qt = 0; qt < 2; ++qt) {
    accSum[qt] = zero4;
#pragma unroll
    for (int dt = 0; dt < 4; ++dt) accO[qt][dt] = zero4;
  }

  short8 onesf;
  {
    short o = (l15 == 0) ? (short)0x3F80 : (short)0;  // bf16 1.0 in B row 0
    onesf = (short8){o, o, o, o, o, o, o, o};
  }

  int clo = (n == 0) ? 2 : 0, chi = (n == 31) ? 4 : 6;
  int nloc = chi - clo, goff = 6 - nloc;
  int m = nloc + 4;
  unsigned short* pw = Pl[wid];

  auto stage = [&](int c, unsigned short* Kl, unsigned short* Vl) {
    bool isg = c >= 6;
#pragma unroll
    for (int i = 0; i < 2; ++i) {
      int seg = wid * 2 + i;
      int r = seg * 8 + (lane >> 3);
      int sl = ((lane & 7) ^ (r & 7)) * 8;
      const unsigned short *ksrc, *vsrc;
      if (!isg) {
        int p0 = (n - 1) * 128 + c * 64;  // in [0, L-64] after chunk trimming
        ksrc = qkv + (size_t)(b * L + p0 + r) * 3072 + 1024 + h * 64 + sl;
        vsrc = v_t + ((size_t)b * 1024 + h * 64 + r) * L + p0 + sl;
      } else {
        int g0 = (c - 6) * 64;
        ksrc = qkv + (size_t)(8192 + b * G + g0 + r) * 3072 + 1024 + h * 64 + sl;
        vsrc = side_v_t + ((size_t)b * 1024 + h * 64 + r) * G + g0 + sl;
      }
      gload_lds16(ksrc, (char*)Kl + seg * 1024);
      gload_lds16(vsrc, (char*)Vl + seg * 1024);
    }
  };

  auto compute = [&](int c, const unsigned short* Kl, const unsigned short* Vl) {
    bool isg = c >= 6;
    int d0 = c * 64 - 128 - wid * 32;  // rel of (key0, wave q0)
    if (!isg) {
      if (d0 >= 159 || d0 <= -191) return;  // wave-chunk fully masked
    }
    bool partial = !isg && !(d0 >= -96 && d0 <= 64);

    f32x4 sacc[2][4];
#pragma unroll
    for (int qt = 0; qt < 2; ++qt)
#pragma unroll
      for (int kt = 0; kt < 4; ++kt) sacc[qt][kt] = zero4;
    __builtin_amdgcn_s_setprio(1);
#pragma unroll
    for (int kk = 0; kk < 2; ++kk) {
      short8 kf[4];
#pragma unroll
      for (int kt = 0; kt < 4; ++kt) {
        int r = kt * 16 + l15;
        kf[kt] = *(const short8*)((const char*)Kl + r * 128 +
                                  ((kk * 64 + lg * 16) ^ ((r & 7) << 4)));
      }
#pragma unroll
      for (int qt = 0; qt < 2; ++qt)
#pragma unroll
        for (int kt = 0; kt < 4; ++kt)
          sacc[qt][kt] = mfma16(qf[qt][kk], kf[kt], sacc[qt][kt]);
    }
    __builtin_amdgcn_s_setprio(0);
    if (partial) {
      int relc = d0 + l15 - rq;
#pragma unroll
      for (int qt = 0; qt < 2; ++qt)
#pragma unroll
        for (int kt = 0; kt < 4; ++kt)
#pragma unroll
          for (int r = 0; r < 4; ++r) {
            int rel = relc + kt * 16 - qt * 16 - r;
            sacc[qt][kt][r] =
                ((unsigned)(rel + 127) <= 254u) ? sacc[qt][kt][r] : -1e30f;
          }
    }
#pragma unroll
    for (int qt = 0; qt < 2; ++qt)
#pragma unroll
      for (int kt = 0; kt < 4; ++kt)
#pragma unroll
        for (int r = 0; r < 4; ++r) {
          float p = __builtin_amdgcn_exp2f(sacc[qt][kt][r]);
          int row = qt * 16 + rq + r;
          int cb = (kt * 16 + l15) * 2;
          *(unsigned short*)((char*)pw + row * 128 +
                             (cb ^ ((row & 7) << 4))) = f2bf(p);
        }
    __builtin_amdgcn_s_setprio(1);
#pragma unroll
    for (int ks = 0; ks < 2; ++ks) {
      short8 pa[2], vb[4];
#pragma unroll
      for (int qt = 0; qt < 2; ++qt) {
        int row = qt * 16 + l15;
        pa[qt] = *(const short8*)((const char*)pw + row * 128 +
                                  ((ks * 64 + lg * 16) ^ ((row & 7) << 4)));
      }
#pragma unroll
      for (int dt = 0; dt < 4; ++dt) {
        int d = dt * 16 + l15;
        vb[dt] = *(const short8*)((const char*)Vl + d * 128 +
                                  ((ks * 64 + lg * 16) ^ ((d & 7) << 4)));
      }
#pragma unroll
      for (int qt = 0; qt < 2; ++qt) {
#pragma unroll
        for (int dt = 0; dt < 4; ++dt)
          accO[qt][dt] = mfma16(pa[qt], vb[dt], accO[qt][dt]);
        accSum[qt] = mfma16(pa[qt], onesf, accSum[qt]);
      }
    }
    __builtin_amdgcn_s_setprio(0);
  };

  auto chunk_of = [&](int i) { return i < nloc ? i + clo : i + goff; };

  stage(chunk_of(0), K0, V0);
  __syncthreads();
  for (int i = 0; i < m; i += 2) {
    if (i + 1 < m) stage(chunk_of(i + 1), K1, V1);
    compute(chunk_of(i), K0, V0);
    __syncthreads();
    if (i + 1 >= m) break;
    if (i + 2 < m) stage(chunk_of(i + 2), K0, V0);
    compute(chunk_of(i + 1), K1, V1);
    __syncthreads();
  }

  size_t rowb = (size_t)b * L + n * 128 + wid * 32;
#pragma unroll
  for (int qt = 0; qt < 2; ++qt) {
    float inv[4];
#pragma unroll
    for (int r = 0; r < 4; ++r) {
      float s = __shfl(accSum[qt][r], lane & 48);  // col 0 lives in l15==0 lanes
      inv[r] = 1.f / (1.f + s);
    }
#pragma unroll
    for (int dt = 0; dt < 4; ++dt) {
      int col = h * 64 + dt * 16 + l15;
#pragma unroll
      for (int r = 0; r < 4; ++r)
        y[(rowb + qt * 16 + rq + r) * 1024 + col] =
            f2bf(accO[qt][dt][r] * inv[r]);
    }
  }
}

// ---------------- launch ----------------
extern "C" void kernel_launch(void* const* d_in, const int* in_sizes, int n_in,
                              void* d_out, int out_size, void* d_ws, size_t ws_size,
                              hipStream_t stream) {
  const float* x  = (const float*)d_in[0];
  const float* wq = (const float*)d_in[1];
  const float* wk = (const float*)d_in[2];
  const float* wv = (const float*)d_in[3];
  const float* wo = (const float*)d_in[4];
  char* ws = (char*)d_ws;
  const size_t MB = 1 << 20;
  unsigned short* xb     = (unsigned short*)(ws);             // 16MB; reused as y
  unsigned short* gb     = (unsigned short*)(ws + 16 * MB);   // 1MB; reused as svt
  unsigned short* wqkv_t = (unsigned short*)(ws + 17 * MB);   // 6MB
  unsigned short* wo_t   = (unsigned short*)(ws + 23 * MB);   // 2MB
  unsigned short* qkvb   = (unsigned short*)(ws + 25 * MB);   // 51MB [8704][3072]
  unsigned short* vt     = (unsigned short*)(ws + 76 * MB);   // 16MB
  unsigned short* svt    = gb;   // gb dead after fused QKV GEMM
  unsigned short* yb     = xb;   // xb dead after fused QKV GEMM

  prep_x_k<<<512, 256, 0, stream>>>(x, xb, gb);  // gb contiguous after xb
  transpose_w4_k<<<dim3(16, 16, 4), 256, 0, stream>>>(wq, wk, wv, wo, wqkv_t, wo_t);
  // fused QKV + side: [8704][1024] x [3072][1024]^T -> [8704][3072]
  gemm256_k<<<34 * 12, 512, 0, stream>>>(xb, wqkv_t, qkvb, 8704, 3072, 1024, 12);
  // V^T: per b, [4096][1024] -> [1024][4096]
  transpose_bf16_k<<<dim3(16, 64, 2), 256, 0, stream>>>(
      qkvb + 2048, 3072, (size_t)4096 * 3072, vt, 4096, (size_t)1024 * 4096);
  // side V^T: per b, [256][1024] -> [1024][256]
  transpose_bf16_k<<<dim3(16, 4, 2), 256, 0, stream>>>(
      qkvb + (size_t)8192 * 3072 + 2048, 3072, (size_t)256 * 3072, svt, 256,
      (size_t)1024 * 256);
  attn_k<<<1024, 256, 0, stream>>>(qkvb, vt, svt, yb);
  // out: [8192][1024] x [1024][1024]^T -> f32 d_out
  gemm_bt_k<true><<<64 * 8, 256, 0, stream>>>(yb, wo_t, d_out, 8192, 1024, 1024, 8);
}

// Round 7
// 161.875 us; speedup vs baseline: 1.0195x; 1.0195x over previous
//
#include <hip/hip_runtime.h>
#include <stdint.h>

#define SC_LOG2E 0.18033688011112042f  // (1/8) * log2(e)

typedef __attribute__((ext_vector_type(8))) short short8;
typedef __attribute__((ext_vector_type(4))) short short4v;
typedef __attribute__((ext_vector_type(4))) float f32x4;

__device__ __forceinline__ unsigned short f2bf(float f) {
  unsigned int u = __float_as_uint(f);
  u += 0x7fffu + ((u >> 16) & 1u);
  return (unsigned short)(u >> 16);
}

__device__ __forceinline__ void gload_lds16(const void* g, void* l) {
  __builtin_amdgcn_global_load_lds((const __attribute__((address_space(1))) void*)g,
                                   (__attribute__((address_space(3))) void*)l,
                                   16, 0, 0);
}

__device__ __forceinline__ f32x4 mfma16(short8 a, short8 b, f32x4 c) {
  return __builtin_amdgcn_mfma_f32_16x16x32_bf16(a, b, c, 0, 0, 0);
}

// ds_read_b64_tr_b16 slot model (m156): each lane addresses its OWN 8-byte slot
// (lane-in-group g at window + g*8B); HW permutes within the 16-lane group so
// lane g receives column g of the group's 128B [4 rows][16 cols] bf16 block:
// elem j = window[j*16 + g].
__device__ __forceinline__ short4v tr_read(const unsigned short* p) {
  short4v r;
  asm volatile("ds_read_b64_tr_b16 %0, %1"
               : "=v"(r)
               : "v"((const __attribute__((address_space(3))) unsigned short*)p));
  return r;
}

__device__ __forceinline__ short8 cat44(short4v lo, short4v hi) {
  return __builtin_shufflevector(lo, hi, 0, 1, 2, 3, 4, 5, 6, 7);
}

// ---------------- prep kernels ----------------

// fused: cast x -> bf16 AND per-16-row block sums -> bf16 (x read once)
__global__ __launch_bounds__(256) void prep_x_k(const float* __restrict__ x,
                                                unsigned short* __restrict__ xb,
                                                unsigned short* __restrict__ gb) {
  int gr = blockIdx.x;   // 0..511 = b*256 + g
  int c4 = threadIdx.x;  // col group of 4
  const float4* p = (const float4*)(x + (size_t)gr * 16384) + c4;
  float4 s = {0.f, 0.f, 0.f, 0.f};
#pragma unroll
  for (int t = 0; t < 16; ++t) {
    float4 v = p[(size_t)t * 256];
    ushort4 o;
    o.x = f2bf(v.x); o.y = f2bf(v.y); o.z = f2bf(v.z); o.w = f2bf(v.w);
    ((ushort4*)xb)[(size_t)(gr * 16 + t) * 256 + c4] = o;
    s.x += v.x; s.y += v.y; s.z += v.z; s.w += v.w;
  }
  ushort4 og;
  og.x = f2bf(s.x); og.y = f2bf(s.y); og.z = f2bf(s.z); og.w = f2bf(s.w);
  ((ushort4*)gb)[(size_t)gr * 256 + c4] = og;
}

// transpose 4x [1024][1024] f32 weights -> bf16 [N][K]; Wq pre-scaled by SC_LOG2E
__global__ __launch_bounds__(256) void transpose_w4_k(
    const float* __restrict__ wq, const float* __restrict__ wk,
    const float* __restrict__ wv, const float* __restrict__ wo,
    unsigned short* __restrict__ wqkv_t, unsigned short* __restrict__ wo_t) {
  __shared__ float tile[64 * 65];
  int z = blockIdx.z;
  const float* src = (z == 0) ? wq : (z == 1) ? wk : (z == 2) ? wv : wo;
  unsigned short* dst = (z == 3) ? wo_t : (wqkv_t + (size_t)z * 1048576);
  float scale = (z == 0) ? SC_LOG2E : 1.0f;
  int tc = blockIdx.x * 64, tr = blockIdx.y * 64;
  int cx = threadIdx.x & 63, ry = threadIdx.x >> 6;
#pragma unroll
  for (int i = 0; i < 16; ++i) {
    int r = ry + i * 4;
    tile[r * 65 + cx] = src[(size_t)(tr + r) * 1024 + tc + cx];
  }
  __syncthreads();
#pragma unroll
  for (int i = 0; i < 16; ++i) {
    int r = ry + i * 4;
    dst[(size_t)(tc + r) * 1024 + tr + cx] = f2bf(tile[cx * 65 + r] * scale);
  }
}

// ---------------- GEMM m97 structure: C[M][N] = A[M][K] * Bt[N][K]^T ----------------
template <bool F32OUT>
__global__ __launch_bounds__(256) void gemm_bt_k(
    const unsigned short* __restrict__ A, const unsigned short* __restrict__ Bt,
    void* __restrict__ Cv, int M, int N, int K, int nbn) {
  __shared__ unsigned short Alds[128 * 64];
  __shared__ unsigned short Blds[128 * 64];
  int bid = blockIdx.x;
  int bm = bid / nbn, bn = bid % nbn;
  int lane = threadIdx.x & 63, wid = threadIdx.x >> 6;
  int wr = wid >> 1, wc = wid & 1;
  int l15 = lane & 15, lg = lane >> 4;

  f32x4 zero4 = {0.f, 0.f, 0.f, 0.f};
  f32x4 acc[4][4];
#pragma unroll
  for (int i = 0; i < 4; ++i)
#pragma unroll
    for (int j = 0; j < 4; ++j) acc[i][j] = zero4;

  int srow[4], scol[4];
#pragma unroll
  for (int i = 0; i < 4; ++i) {
    int seg = wid * 4 + i;
    int r = seg * 8 + (lane >> 3);
    srow[i] = r;
    scol[i] = ((lane & 7) ^ (r & 7)) * 8;
  }
  size_t arow0 = (size_t)bm * 128, brow0 = (size_t)bn * 128;

  int ksteps = K >> 6;
  for (int ks = 0; ks < ksteps; ++ks) {
    int k0 = ks << 6;
#pragma unroll
    for (int i = 0; i < 4; ++i) {
      gload_lds16(A + (arow0 + srow[i]) * K + k0 + scol[i],
                  (char*)Alds + (wid * 4 + i) * 1024);
      gload_lds16(Bt + (brow0 + srow[i]) * K + k0 + scol[i],
                  (char*)Blds + (wid * 4 + i) * 1024);
    }
    __syncthreads();
#pragma unroll
    for (int kk = 0; kk < 2; ++kk) {
      short8 af[4], bfr[4];
#pragma unroll
      for (int mi = 0; mi < 4; ++mi) {
        int r = wr * 64 + mi * 16 + l15;
        af[mi] = *(const short8*)((const char*)Alds + r * 128 +
                                  ((kk * 64 + lg * 16) ^ ((r & 7) << 4)));
      }
#pragma unroll
      for (int ni = 0; ni < 4; ++ni) {
        int r = wc * 64 + ni * 16 + l15;
        bfr[ni] = *(const short8*)((const char*)Blds + r * 128 +
                                   ((kk * 64 + lg * 16) ^ ((r & 7) << 4)));
      }
#pragma unroll
      for (int mi = 0; mi < 4; ++mi)
#pragma unroll
        for (int ni = 0; ni < 4; ++ni)
          acc[mi][ni] = mfma16(af[mi], bfr[ni], acc[mi][ni]);
    }
    __syncthreads();
  }
  int rq = lg << 2;
#pragma unroll
  for (int mi = 0; mi < 4; ++mi) {
    size_t row = arow0 + wr * 64 + mi * 16 + rq;
#pragma unroll
    for (int ni = 0; ni < 4; ++ni) {
      size_t col = brow0 + wc * 64 + ni * 16 + l15;
#pragma unroll
      for (int r = 0; r < 4; ++r) {
        if (F32OUT)
          ((float*)Cv)[(row + r) * N + col] = acc[mi][ni][r];
        else
          ((unsigned short*)Cv)[(row + r) * N + col] = f2bf(acc[mi][ni][r]);
      }
    }
  }
}

// ---------------- fused local+global flash attention (m=0 softmax) ----------------
// grid = B*H*nb (n fastest); block = 256 (4 waves x 32 q-rows)
// qkv: [8704][3072] = rows 0..8191 token q|k|v, rows 8192..8703 side g-rows
// V staged straight from qkv into tr-read-ready subtiled LDS (T10); no V^T buffer.
// V LDS layout: subtile S = di*16+ks*8+lgg*2+half, each [4 keys][16 d] row-major
// (64 elems); keys = ks*32+lgg*8+half*4+{0..3}, d = di*16+{0..15}.
__global__ __launch_bounds__(256) void attn_k(
    const unsigned short* __restrict__ qkv,
    unsigned short* __restrict__ y) {  // [B*L][1024]
  const int L = 4096, G = 256;
  __shared__ unsigned short K0[4096], V0[4096];  // K: [key][d] swizzled; V: subtiled
  __shared__ unsigned short K1[4096], V1[4096];
  __shared__ unsigned short Pl[4][2048];         // per-wave P [32 q][64 k]

  int bid = blockIdx.x;
  int n = bid & 31, h = (bid >> 5) & 15, b = bid >> 9;
  int lane = threadIdx.x & 63, wid = threadIdx.x >> 6;
  int l15 = lane & 15, lg = lane >> 4, rq = lg << 2;

  short8 qf[2][2];
  {
    size_t rowb = (size_t)b * L + n * 128 + wid * 32;
#pragma unroll
    for (int qt = 0; qt < 2; ++qt)
#pragma unroll
      for (int kk = 0; kk < 2; ++kk)
        qf[qt][kk] = *(const short8*)(qkv + (rowb + qt * 16 + l15) * 3072 +
                                      h * 64 + kk * 32 + lg * 8);
  }

  f32x4 zero4 = {0.f, 0.f, 0.f, 0.f};
  f32x4 accO[2][4], accSum[2];
#pragma unroll
  for (int qt = 0; qt < 2; ++qt) {
    accSum[qt] = zero4;
#pragma unroll
    for (int dt = 0; dt < 4; ++dt) accO[qt][dt] = zero4;
  }

  short8 onesf;
  {
    short o = (l15 == 0) ? (short)0x3F80 : (short)0;  // bf16 1.0 in B row 0
    onesf = (short8){o, o, o, o, o, o, o, o};
  }

  int clo = (n == 0) ? 2 : 0, chi = (n == 31) ? 4 : 6;
  int nloc = chi - clo, goff = 6 - nloc;
  int m = nloc + 4;
  unsigned short* pw = Pl[wid];

  auto stage = [&](int c, unsigned short* Kl, unsigned short* Vl) {
    bool isg = c >= 6;
    int rowbase;
    if (!isg)
      rowbase = b * L + (n - 1) * 128 + c * 64;  // in [0, L-64] after chunk trim
    else
      rowbase = 8192 + b * G + (c - 6) * 64;
#pragma unroll
    for (int i = 0; i < 2; ++i) {
      int seg = wid * 2 + i;
      // ---- K: [key][d] row-major with XOR swizzle (pre-swizzled source) ----
      int r = seg * 8 + (lane >> 3);
      int sl = ((lane & 7) ^ (r & 7)) * 8;
      gload_lds16(qkv + (size_t)(rowbase + r) * 3072 + 1024 + h * 64 + sl,
                  (char*)Kl + seg * 1024);
      // ---- V: subtiled [4k][16d] for tr_read; linear LDS dest, decode src ----
      // e = seg*512 + lane*8 -> S = e>>6, row = (lane&7)>>1, dhalf = (lane&1)*8
      int S = seg * 8 + (lane >> 3);
      int di = S >> 4, ks = (S >> 3) & 1, lgg = (S >> 1) & 3, half = S & 1;
      int k = ks * 32 + lgg * 8 + half * 4 + ((lane & 7) >> 1);
      int d = di * 16 + (lane & 1) * 8;
      gload_lds16(qkv + (size_t)(rowbase + k) * 3072 + 2048 + h * 64 + d,
                  (char*)Vl + seg * 1024);
    }
  };

  auto compute = [&](int c, const unsigned short* Kl, const unsigned short* Vl) {
    bool isg = c >= 6;
    int d0 = c * 64 - 128 - wid * 32;  // rel of (key0, wave q0)
    if (!isg) {
      if (d0 >= 159 || d0 <= -191) return;  // wave-chunk fully masked
    }
    bool partial = !isg && !(d0 >= -96 && d0 <= 64);

    f32x4 sacc[2][4];
#pragma unroll
    for (int qt = 0; qt < 2; ++qt)
#pragma unroll
      for (int kt = 0; kt < 4; ++kt) sacc[qt][kt] = zero4;
    __builtin_amdgcn_s_setprio(1);
#pragma unroll
    for (int kk = 0; kk < 2; ++kk) {
      short8 kf[4];
#pragma unroll
      for (int kt = 0; kt < 4; ++kt) {
        int r = kt * 16 + l15;
        kf[kt] = *(const short8*)((const char*)Kl + r * 128 +
                                  ((kk * 64 + lg * 16) ^ ((r & 7) << 4)));
      }
#pragma unroll
      for (int qt = 0; qt < 2; ++qt)
#pragma unroll
        for (int kt = 0; kt < 4; ++kt)
          sacc[qt][kt] = mfma16(qf[qt][kk], kf[kt], sacc[qt][kt]);
    }
    __builtin_amdgcn_s_setprio(0);
    if (partial) {
      int relc = d0 + l15 - rq;
#pragma unroll
      for (int qt = 0; qt < 2; ++qt)
#pragma unroll
        for (int kt = 0; kt < 4; ++kt)
#pragma unroll
          for (int r = 0; r < 4; ++r) {
            int rel = relc + kt * 16 - qt * 16 - r;
            sacc[qt][kt][r] =
                ((unsigned)(rel + 127) <= 254u) ? sacc[qt][kt][r] : -1e30f;
          }
    }
#pragma unroll
    for (int qt = 0; qt < 2; ++qt)
#pragma unroll
      for (int kt = 0; kt < 4; ++kt)
#pragma unroll
        for (int r = 0; r < 4; ++r) {
          float p = __builtin_amdgcn_exp2f(sacc[qt][kt][r]);
          int row = qt * 16 + rq + r;
          int cb = (kt * 16 + l15) * 2;
          *(unsigned short*)((char*)pw + row * 128 +
                             (cb ^ ((row & 7) << 4))) = f2bf(p);
        }
    // ---- O += P V via tr_read V fragments; rowsum += P * ones ----
#pragma unroll
    for (int ks = 0; ks < 2; ++ks) {
      short8 pa[2];
#pragma unroll
      for (int qt = 0; qt < 2; ++qt) {
        int row = qt * 16 + l15;
        pa[qt] = *(const short8*)((const char*)pw + row * 128 +
                                  ((ks * 64 + lg * 16) ^ ((row & 7) << 4)));
      }
      short4v vlo[4], vhi[4];
#pragma unroll
      for (int dt = 0; dt < 4; ++dt) {
        // lane's OWN 8B slot: subtile S0 = ((dt*2+ks)*4+lg)*2, slot l15 (x4 elems)
        const unsigned short* base =
            Vl + (((dt * 2 + ks) * 4 + lg) * 2) * 64 + l15 * 4;
        vlo[dt] = tr_read(base);        // half 0: keys lg*8+0..3 (col l15)
        vhi[dt] = tr_read(base + 64);   // half 1: keys lg*8+4..7
      }
      asm volatile("s_waitcnt lgkmcnt(0)" ::: "memory");
      __builtin_amdgcn_sched_barrier(0);
      __builtin_amdgcn_s_setprio(1);
#pragma unroll
      for (int qt = 0; qt < 2; ++qt) {
#pragma unroll
        for (int dt = 0; dt < 4; ++dt)
          accO[qt][dt] = mfma16(pa[qt], cat44(vlo[dt], vhi[dt]), accO[qt][dt]);
        accSum[qt] = mfma16(pa[qt], onesf, accSum[qt]);
      }
      __builtin_amdgcn_s_setprio(0);
    }
  };

  auto chunk_of = [&](int i) { return i < nloc ? i + clo : i + goff; };

  stage(chunk_of(0), K0, V0);
  __syncthreads();
  for (int i = 0; i < m; i += 2) {
    if (i + 1 < m) stage(chunk_of(i + 1), K1, V1);
    compute(chunk_of(i), K0, V0);
    __syncthreads();
    if (i + 1 >= m) break;
    if (i + 2 < m) stage(chunk_of(i + 2), K0, V0);
    compute(chunk_of(i + 1), K1, V1);
    __syncthreads();
  }

  size_t rowb = (size_t)b * L + n * 128 + wid * 32;
#pragma unroll
  for (int qt = 0; qt < 2; ++qt) {
    float inv[4];
#pragma unroll
    for (int r = 0; r < 4; ++r) {
      float s = __shfl(accSum[qt][r], lane & 48);  // col 0 lives in l15==0 lanes
      inv[r] = 1.f / (1.f + s);
    }
#pragma unroll
    for (int dt = 0; dt < 4; ++dt) {
      int col = h * 64 + dt * 16 + l15;
#pragma unroll
      for (int r = 0; r < 4; ++r)
        y[(rowb + qt * 16 + rq + r) * 1024 + col] =
            f2bf(accO[qt][dt][r] * inv[r]);
    }
  }
}

// ---------------- launch ----------------
extern "C" void kernel_launch(void* const* d_in, const int* in_sizes, int n_in,
                              void* d_out, int out_size, void* d_ws, size_t ws_size,
                              hipStream_t stream) {
  const float* x  = (const float*)d_in[0];
  const float* wq = (const float*)d_in[1];
  const float* wk = (const float*)d_in[2];
  const float* wv = (const float*)d_in[3];
  const float* wo = (const float*)d_in[4];
  char* ws = (char*)d_ws;
  const size_t MB = 1 << 20;
  unsigned short* xb     = (unsigned short*)(ws);             // 16MB; reused as y
  unsigned short* gb     = (unsigned short*)(ws + 16 * MB);   // 1MB (contig with xb)
  unsigned short* wqkv_t = (unsigned short*)(ws + 17 * MB);   // 6MB
  unsigned short* wo_t   = (unsigned short*)(ws + 23 * MB);   // 2MB
  unsigned short* qkvb   = (unsigned short*)(ws + 25 * MB);   // 51MB [8704][3072]
  unsigned short* yb     = xb;  // xb dead after fused QKV GEMM

  prep_x_k<<<512, 256, 0, stream>>>(x, xb, gb);
  transpose_w4_k<<<dim3(16, 16, 4), 256, 0, stream>>>(wq, wk, wv, wo, wqkv_t, wo_t);
  // fused QKV + side: [8704][1024] x [3072][1024]^T -> [8704][3072]  (m97, 3 blk/CU)
  gemm_bt_k<false><<<68 * 24, 256, 0, stream>>>(xb, wqkv_t, qkvb, 8704, 3072, 1024, 24);
  attn_k<<<1024, 256, 0, stream>>>(qkvb, yb);
  // out: [8192][1024] x [1024][1024]^T -> f32 d_out
  gemm_bt_k<true><<<64 * 8, 256, 0, stream>>>(yb, wo_t, d_out, 8192, 1024, 1024, 8);
}